// Round 10
// baseline (416.591 us; speedup 1.0000x reference)
//
#include <hip/hip_runtime.h>
#include <math.h>

#define FEAT 128
#define HID  64
#define BSH  7                 // 128 dst-nodes per bucket
#define BNODES (1 << BSH)
#define PB   64                // partition blocks (64 -> 128B runs, less line sharing)
#define SRCM ((1u << 25) - 1)  // src in low 25 bits, dst_local in high 7

// ---------------- stage 1: edge partition by dst-bucket ----------------

__global__ void part_hist_k(const int* __restrict__ dst, int* __restrict__ table,
                            int e, int nb) {
    __shared__ int lcnt[1024];
    for (int i = threadIdx.x; i < nb; i += 256) lcnt[i] = 0;
    __syncthreads();
    int eb = (e + PB - 1) / PB;
    int lo = blockIdx.x * eb, hi = min(lo + eb, e);
    for (int i = lo + threadIdx.x; i < hi; i += 256)
        atomicAdd(&lcnt[dst[i] >> BSH], 1);
    __syncthreads();
    for (int k = threadIdx.x; k < nb; k += 256)
        table[k * PB + blockIdx.x] = lcnt[k];
}

__global__ void scan1_k(int* __restrict__ data, int* __restrict__ aux, int L) {
    __shared__ int s[1024];
    int gid = blockIdx.x * 1024 + threadIdx.x;
    int v = (gid < L) ? data[gid] : 0;
    s[threadIdx.x] = v;
    __syncthreads();
    for (int off = 1; off < 1024; off <<= 1) {
        int t = (threadIdx.x >= off) ? s[threadIdx.x - off] : 0;
        __syncthreads();
        s[threadIdx.x] += t;
        __syncthreads();
    }
    if (gid < L) data[gid] = s[threadIdx.x] - v;            // exclusive in block
    if (threadIdx.x == 1023) aux[blockIdx.x] = s[1023];     // block total
}

__global__ void scan2_k(int* aux, int naux) {
    __shared__ int s[1024];
    int v = (threadIdx.x < naux) ? aux[threadIdx.x] : 0;
    s[threadIdx.x] = v;
    __syncthreads();
    for (int off = 1; off < 1024; off <<= 1) {
        int t = (threadIdx.x >= off) ? s[threadIdx.x - off] : 0;
        __syncthreads();
        s[threadIdx.x] += t;
        __syncthreads();
    }
    if (threadIdx.x < naux) aux[threadIdx.x] = s[threadIdx.x] - v;
}

__global__ void part_scatter_k(const int* __restrict__ src, const int* __restrict__ dst,
                               const int* __restrict__ table, const int* __restrict__ aux,
                               unsigned* __restrict__ packed, int e, int nb) {
    __shared__ int loff[1024];
    for (int k = threadIdx.x; k < nb; k += 256) {
        int idx = k * PB + blockIdx.x;
        loff[k] = table[idx] + aux[idx >> 10];
    }
    __syncthreads();
    int eb = (e + PB - 1) / PB;
    int lo = blockIdx.x * eb, hi = min(lo + eb, e);
    for (int i = lo + threadIdx.x; i < hi; i += 256) {
        int d = dst[i];
        int p = atomicAdd(&loff[d >> BSH], 1);
        packed[p] = ((unsigned)(d & (BNODES - 1)) << 25) | (unsigned)src[i];
    }
}

// ---------------- stage 2: per-bucket counting sort -> per-node CSR + dinv ----

__global__ void bucket_sort_k(const unsigned* __restrict__ packed,
                              const int* __restrict__ table, const int* __restrict__ aux,
                              int* __restrict__ col, int* __restrict__ rowptr,
                              float* __restrict__ dinv, int n, int e, int nb) {
    __shared__ int cnt[BNODES];
    __shared__ int s[BNODES];
    __shared__ int cur[BNODES];
    const int k = blockIdx.x;
    const int t = threadIdx.x;
    if (t < BNODES) cnt[t] = 0;
    __syncthreads();
    int i0 = k * PB;
    int i1 = (k + 1) * PB;
    const int bs = table[i0] + aux[i0 >> 10];
    const int be = (k + 1 < nb) ? (table[i1] + aux[i1 >> 10]) : e;
    for (int i = bs + t; i < be; i += 256)
        atomicAdd(&cnt[packed[i] >> 25], 1);
    __syncthreads();
    if (t < BNODES) s[t] = cnt[t];
    __syncthreads();
    for (int off = 1; off < BNODES; off <<= 1) {
        int v = (t < BNODES && t >= off) ? s[t - off] : 0;
        __syncthreads();
        if (t < BNODES) s[t] += v;
        __syncthreads();
    }
    if (t < BNODES) {
        int base = bs + s[t] - cnt[t];
        cur[t] = base;
        int node = (k << BSH) + t;
        if (node < n) {
            rowptr[node] = base;
            dinv[node] = 1.0f / sqrtf(1.0f + (float)cnt[t]);
            if (node == n - 1) rowptr[n] = base + cnt[t];
        }
    }
    __syncthreads();
    for (int i = bs + t; i < be; i += 256) {
        unsigned u = packed[i];
        int p = atomicAdd(&cur[u >> 25], 1);
        col[p] = (int)(u & SRCM);
    }
}

// ---------------- dense transform: out[n,64] = (X[n,K] @ W[K,64]) * dinv[row] ----------------

template<int K>
__global__ __launch_bounds__(256, (K == 128) ? 3 : 4)
void gemm_tile_k(const float* __restrict__ X, const float* __restrict__ W,
                 const float* __restrict__ dinv, float* __restrict__ out, int n) {
    __shared__ float sX[64][K + 4];
    __shared__ float sW[64][64];       // one 64-row slab of W
    const int row0 = blockIdx.x * 64;
    const int t  = threadIdx.x;
    const int tx = t & 15;
    const int ty = t >> 4;
    constexpr int KSH = (K == 128) ? 7 : 6;

    const float* xb = X + (size_t)row0 * K;
#pragma unroll
    for (int it = 0; it < K / 16; ++it) {
        int fl = it * 1024 + t * 4;
        int r  = fl >> KSH;
        int k  = fl & (K - 1);
        float4 v = make_float4(0.f, 0.f, 0.f, 0.f);
        if (row0 + r < n) v = *(const float4*)(xb + fl);
        *(float4*)&sX[r][k] = v;
    }

    float acc[4][4] = {};
#pragma unroll
    for (int ph = 0; ph < K / 64; ++ph) {
        __syncthreads();
#pragma unroll
        for (int it = 0; it < 4; ++it) {
            int fl = it * 1024 + t * 4;
            *(float4*)&sW[fl >> 6][fl & 63] = *(const float4*)(W + ph * 64 * HID + fl);
        }
        __syncthreads();

#pragma unroll 8
        for (int k = 0; k < 64; k += 4) {
            float4 a[4], b[4];
#pragma unroll
            for (int i = 0; i < 4; i++) a[i] = *(float4*)&sX[ty * 4 + i][ph * 64 + k];
#pragma unroll
            for (int j = 0; j < 4; j++) b[j] = *(float4*)&sW[k + j][tx * 4];
#pragma unroll
            for (int i = 0; i < 4; i++) {
                acc[i][0] = fmaf(a[i].x, b[0].x, acc[i][0]);
                acc[i][1] = fmaf(a[i].x, b[0].y, acc[i][1]);
                acc[i][2] = fmaf(a[i].x, b[0].z, acc[i][2]);
                acc[i][3] = fmaf(a[i].x, b[0].w, acc[i][3]);
                acc[i][0] = fmaf(a[i].y, b[1].x, acc[i][0]);
                acc[i][1] = fmaf(a[i].y, b[1].y, acc[i][1]);
                acc[i][2] = fmaf(a[i].y, b[1].z, acc[i][2]);
                acc[i][3] = fmaf(a[i].y, b[1].w, acc[i][3]);
                acc[i][0] = fmaf(a[i].z, b[2].x, acc[i][0]);
                acc[i][1] = fmaf(a[i].z, b[2].y, acc[i][1]);
                acc[i][2] = fmaf(a[i].z, b[2].z, acc[i][2]);
                acc[i][3] = fmaf(a[i].z, b[2].w, acc[i][3]);
                acc[i][0] = fmaf(a[i].w, b[3].x, acc[i][0]);
                acc[i][1] = fmaf(a[i].w, b[3].y, acc[i][1]);
                acc[i][2] = fmaf(a[i].w, b[3].z, acc[i][2]);
                acc[i][3] = fmaf(a[i].w, b[3].w, acc[i][3]);
            }
        }
    }

#pragma unroll
    for (int i = 0; i < 4; i++) {
        int gr = row0 + ty * 4 + i;
        if (gr < n) {
            float sc = dinv[gr];
            *(float4*)(out + (size_t)gr * HID + tx * 4) =
                make_float4(acc[i][0] * sc, acc[i][1] * sc, acc[i][2] * sc, acc[i][3] * sc);
        }
    }
}

// ---------------- CSR gather aggregation (fused selfloop + bias + relu [+ logits]) ----
// 16-deep gather unroll: col reads are wave-uniform (scalar cache); the 16
// vector gathers stay in flight together for MLP.

template<bool LOGITS>
__global__ void gather_k(const float* __restrict__ tS, const int* __restrict__ rowptr,
                         const int* __restrict__ col, const float* __restrict__ dinv,
                         const float* __restrict__ b, float* __restrict__ out,
                         const float* __restrict__ Wa, const float* __restrict__ ba,
                         float* __restrict__ logits, int n) {
    int node = (int)((blockIdx.x * (size_t)blockDim.x + threadIdx.x) >> 6);
    int lane = threadIdx.x & 63;
    if (node >= n) return;
    int beg = rowptr[node], end = rowptr[node + 1];
    const float* tl = tS + lane;
    float acc = tl[(size_t)node * HID];   // self-loop term
    int e = beg;
    for (; e + 16 <= end; e += 16) {
        int s[16];
        float v[16];
#pragma unroll
        for (int j = 0; j < 16; j++) s[j] = col[e + j];
#pragma unroll
        for (int j = 0; j < 16; j++) v[j] = tl[(size_t)s[j] * HID];
        float t0 = ((v[0] + v[1]) + (v[2] + v[3])) + ((v[4] + v[5]) + (v[6] + v[7]));
        float t1 = ((v[8] + v[9]) + (v[10] + v[11])) + ((v[12] + v[13]) + (v[14] + v[15]));
        acc += t0 + t1;
    }
    for (; e + 4 <= end; e += 4) {
        int s0 = col[e], s1 = col[e + 1], s2 = col[e + 2], s3 = col[e + 3];
        float v0 = tl[(size_t)s0 * HID];
        float v1 = tl[(size_t)s1 * HID];
        float v2 = tl[(size_t)s2 * HID];
        float v3 = tl[(size_t)s3 * HID];
        acc += (v0 + v1) + (v2 + v3);
    }
    for (; e < end; ++e) acc += tl[(size_t)col[e] * HID];
    float h = fmaxf(fmaf(dinv[node], acc, b[lane]), 0.0f);
    out[(size_t)node * HID + lane] = h;
    if (LOGITS) {
        float p = h * Wa[lane];
#pragma unroll
        for (int off = 32; off > 0; off >>= 1) p += __shfl_down(p, off);
        if (lane == 0) logits[node] = p + ba[0];
    }
}

// ---------------- heads ----------------

__global__ void pool_k(const float* __restrict__ h, const int* __restrict__ batch,
                       float* __restrict__ pooled, float* __restrict__ counts, int n) {
    int lane = threadIdx.x & 63;
    int wave = threadIdx.x >> 6;
    int start = blockIdx.x * 256 + wave * 64;
    int end   = min(start + 64, n);
    if (start >= end) return;
    float acc = 0.0f;
    int curg = -1, cnt = 0;
    for (int i = start; i < end; i++) {
        int g = batch[i];
        if (g != curg) {
            if (curg >= 0) {
                atomicAdd(&pooled[curg * HID + lane], acc);
                if (lane == 0) atomicAdd(&counts[curg], (float)cnt);
            }
            curg = g; acc = 0.0f; cnt = 0;
        }
        acc += h[(size_t)i * HID + lane];
        cnt++;
    }
    atomicAdd(&pooled[curg * HID + lane], acc);
    if (lane == 0) atomicAdd(&counts[curg], (float)cnt);
}

__global__ void value_k(const float* __restrict__ pooled, const float* __restrict__ counts,
                        const float* __restrict__ Wc, const float* __restrict__ bc,
                        float* __restrict__ val, int g) {
    int gw   = (int)((blockIdx.x * (size_t)blockDim.x + threadIdx.x) >> 6);
    int lane = threadIdx.x & 63;
    if (gw >= g) return;
    float cnt = fmaxf(counts[gw], 1.0f);
    float p = (pooled[gw * HID + lane] / cnt) * Wc[lane];
#pragma unroll
    for (int off = 32; off > 0; off >>= 1) p += __shfl_down(p, off);
    if (lane == 0) val[gw] = p + bc[0];
}

extern "C" void kernel_launch(void* const* d_in, const int* in_sizes, int n_in,
                              void* d_out, int out_size, void* d_ws, size_t ws_size,
                              hipStream_t stream) {
    const float* x     = (const float*)d_in[0];
    const int*   ei    = (const int*)d_in[1];
    const int*   batch = (const int*)d_in[2];
    const float* W1    = (const float*)d_in[3];
    const float* b1    = (const float*)d_in[4];
    const float* W2    = (const float*)d_in[5];
    const float* b2    = (const float*)d_in[6];
    const float* Wa    = (const float*)d_in[7];
    const float* ba    = (const float*)d_in[8];
    const float* Wc    = (const float*)d_in[9];
    const float* bc    = (const float*)d_in[10];

    const int n = in_sizes[0] / FEAT;   // 100000
    const int e = in_sizes[1] / 2;      // 1600000
    const int g = out_size - n;         // 64
    const int* src = ei;
    const int* dst = ei + e;

    const int nb = (n + BNODES - 1) >> BSH;   // buckets (782)
    const int L  = nb * PB;                    // offset table length

    // workspace layout (packed aliases bufA: dead before first gemm)
    float*    ws     = (float*)d_ws;
    float*    dinv   = ws;                               // n
    float*    bufA   = dinv + n;                         // n*HID  (tS)
    float*    bufB   = bufA + (size_t)n * HID;           // n*HID  (h)
    float*    pooled = bufB + (size_t)n * HID;           // g*HID
    float*    counts = pooled + (size_t)g * HID;         // g
    int*      table  = (int*)(counts + g);               // L
    int*      aux    = table + L;                        // 1024
    int*      rowptr = aux + 1024;                       // n+1
    int*      col    = rowptr + n + 1;                   // e
    unsigned* packed = (unsigned*)bufA;                  // e (aliased, transient)

    const int B = 256;
    const int gridT = (n + 63) / 64;
    const int gridG = (int)(((size_t)n * 64 + B - 1) / B);   // wave per node
    const int nb1   = (L + 1023) / 1024;

    hipMemsetAsync(pooled, 0, (size_t)(g * HID + g) * sizeof(float), stream);

    // two-level CSR build: bucket partition -> in-bucket counting sort
    part_hist_k<<<PB, B, 0, stream>>>(dst, table, e, nb);
    scan1_k<<<nb1, 1024, 0, stream>>>(table, aux, L);
    scan2_k<<<1, 1024, 0, stream>>>(aux, nb1);
    part_scatter_k<<<PB, B, 0, stream>>>(src, dst, table, aux, packed, e, nb);
    bucket_sort_k<<<nb, B, 0, stream>>>(packed, table, aux, col, rowptr, dinv, n, e, nb);

    // layer 1
    gemm_tile_k<FEAT><<<gridT, B, 0, stream>>>(x, W1, dinv, bufA, n);
    gather_k<false><<<gridG, B, 0, stream>>>(bufA, rowptr, col, dinv, b1, bufB,
                                             nullptr, nullptr, nullptr, n);

    // layer 2 (logits fused into gather epilogue)
    gemm_tile_k<HID><<<gridT, B, 0, stream>>>(bufB, W2, dinv, bufA, n);
    gather_k<true><<<gridG, B, 0, stream>>>(bufA, rowptr, col, dinv, b2, bufB,
                                            Wa, ba, (float*)d_out, n);

    // heads
    pool_k<<<(n + 255) / 256, B, 0, stream>>>(bufB, batch, pooled, counts, n);
    value_k<<<(g * 64 + B - 1) / B, B, 0, stream>>>(pooled, counts, Wc, bc, (float*)d_out + n, g);
}

// Round 11
// 360.637 us; speedup vs baseline: 1.1552x; 1.1552x over previous
//
#include <hip/hip_runtime.h>
#include <math.h>

#define FEAT 128
#define HID  64
#define BSH  7                 // 128 dst-nodes per bucket
#define BNODES (1 << BSH)
#define PB   256               // partition blocks (256: full-chip parallelism — PB=64 regressed 2.5x)
#define SRCM ((1u << 25) - 1)  // src in low 25 bits, dst_local in high 7

// ---------------- stage 1: edge partition by dst-bucket ----------------

__global__ void part_hist_k(const int* __restrict__ dst, int* __restrict__ table,
                            int e, int nb) {
    __shared__ int lcnt[1024];
    for (int i = threadIdx.x; i < nb; i += 256) lcnt[i] = 0;
    __syncthreads();
    int eb = (e + PB - 1) / PB;
    int lo = blockIdx.x * eb, hi = min(lo + eb, e);
    for (int i = lo + threadIdx.x; i < hi; i += 256)
        atomicAdd(&lcnt[dst[i] >> BSH], 1);
    __syncthreads();
    for (int k = threadIdx.x; k < nb; k += 256)
        table[k * PB + blockIdx.x] = lcnt[k];
}

__global__ void scan1_k(int* __restrict__ data, int* __restrict__ aux, int L) {
    __shared__ int s[1024];
    int gid = blockIdx.x * 1024 + threadIdx.x;
    int v = (gid < L) ? data[gid] : 0;
    s[threadIdx.x] = v;
    __syncthreads();
    for (int off = 1; off < 1024; off <<= 1) {
        int t = (threadIdx.x >= off) ? s[threadIdx.x - off] : 0;
        __syncthreads();
        s[threadIdx.x] += t;
        __syncthreads();
    }
    if (gid < L) data[gid] = s[threadIdx.x] - v;            // exclusive in block
    if (threadIdx.x == 1023) aux[blockIdx.x] = s[1023];     // block total
}

__global__ void scan2_k(int* aux, int naux) {
    __shared__ int s[1024];
    int v = (threadIdx.x < naux) ? aux[threadIdx.x] : 0;
    s[threadIdx.x] = v;
    __syncthreads();
    for (int off = 1; off < 1024; off <<= 1) {
        int t = (threadIdx.x >= off) ? s[threadIdx.x - off] : 0;
        __syncthreads();
        s[threadIdx.x] += t;
        __syncthreads();
    }
    if (threadIdx.x < naux) aux[threadIdx.x] = s[threadIdx.x] - v;
}

__global__ void part_scatter_k(const int* __restrict__ src, const int* __restrict__ dst,
                               const int* __restrict__ table, const int* __restrict__ aux,
                               unsigned* __restrict__ packed, int e, int nb) {
    __shared__ int loff[1024];
    for (int k = threadIdx.x; k < nb; k += 256) {
        int idx = k * PB + blockIdx.x;
        loff[k] = table[idx] + aux[idx >> 10];
    }
    __syncthreads();
    int eb = (e + PB - 1) / PB;
    int lo = blockIdx.x * eb, hi = min(lo + eb, e);
    for (int i = lo + threadIdx.x; i < hi; i += 256) {
        int d = dst[i];
        int p = atomicAdd(&loff[d >> BSH], 1);
        packed[p] = ((unsigned)(d & (BNODES - 1)) << 25) | (unsigned)src[i];
    }
}

// ---------------- stage 2: per-bucket counting sort -> per-node CSR + dinv ----

__global__ void bucket_sort_k(const unsigned* __restrict__ packed,
                              const int* __restrict__ table, const int* __restrict__ aux,
                              int* __restrict__ col, int* __restrict__ rowptr,
                              float* __restrict__ dinv, int n, int e, int nb) {
    __shared__ int cnt[BNODES];
    __shared__ int s[BNODES];
    __shared__ int cur[BNODES];
    const int k = blockIdx.x;
    const int t = threadIdx.x;
    if (t < BNODES) cnt[t] = 0;
    __syncthreads();
    int i0 = k * PB;
    int i1 = (k + 1) * PB;
    const int bs = table[i0] + aux[i0 >> 10];
    const int be = (k + 1 < nb) ? (table[i1] + aux[i1 >> 10]) : e;
    for (int i = bs + t; i < be; i += 256)
        atomicAdd(&cnt[packed[i] >> 25], 1);
    __syncthreads();
    if (t < BNODES) s[t] = cnt[t];
    __syncthreads();
    for (int off = 1; off < BNODES; off <<= 1) {
        int v = (t < BNODES && t >= off) ? s[t - off] : 0;
        __syncthreads();
        if (t < BNODES) s[t] += v;
        __syncthreads();
    }
    if (t < BNODES) {
        int base = bs + s[t] - cnt[t];
        cur[t] = base;
        int node = (k << BSH) + t;
        if (node < n) {
            rowptr[node] = base;
            dinv[node] = 1.0f / sqrtf(1.0f + (float)cnt[t]);
            if (node == n - 1) rowptr[n] = base + cnt[t];
        }
    }
    __syncthreads();
    for (int i = bs + t; i < be; i += 256) {
        unsigned u = packed[i];
        int p = atomicAdd(&cur[u >> 25], 1);
        col[p] = (int)(u & SRCM);
    }
}

// ---------------- dense transform: out[n,64] = (X[n,K] @ W[K,64]) * dinv[row] ----------------

template<int K>
__global__ __launch_bounds__(256, (K == 128) ? 3 : 4)
void gemm_tile_k(const float* __restrict__ X, const float* __restrict__ W,
                 const float* __restrict__ dinv, float* __restrict__ out, int n) {
    __shared__ float sX[64][K + 4];
    __shared__ float sW[64][64];       // one 64-row slab of W
    const int row0 = blockIdx.x * 64;
    const int t  = threadIdx.x;
    const int tx = t & 15;
    const int ty = t >> 4;
    constexpr int KSH = (K == 128) ? 7 : 6;

    const float* xb = X + (size_t)row0 * K;
#pragma unroll
    for (int it = 0; it < K / 16; ++it) {
        int fl = it * 1024 + t * 4;
        int r  = fl >> KSH;
        int k  = fl & (K - 1);
        float4 v = make_float4(0.f, 0.f, 0.f, 0.f);
        if (row0 + r < n) v = *(const float4*)(xb + fl);
        *(float4*)&sX[r][k] = v;
    }

    float acc[4][4] = {};
#pragma unroll
    for (int ph = 0; ph < K / 64; ++ph) {
        __syncthreads();
#pragma unroll
        for (int it = 0; it < 4; ++it) {
            int fl = it * 1024 + t * 4;
            *(float4*)&sW[fl >> 6][fl & 63] = *(const float4*)(W + ph * 64 * HID + fl);
        }
        __syncthreads();

#pragma unroll 8
        for (int k = 0; k < 64; k += 4) {
            float4 a[4], b[4];
#pragma unroll
            for (int i = 0; i < 4; i++) a[i] = *(float4*)&sX[ty * 4 + i][ph * 64 + k];
#pragma unroll
            for (int j = 0; j < 4; j++) b[j] = *(float4*)&sW[k + j][tx * 4];
#pragma unroll
            for (int i = 0; i < 4; i++) {
                acc[i][0] = fmaf(a[i].x, b[0].x, acc[i][0]);
                acc[i][1] = fmaf(a[i].x, b[0].y, acc[i][1]);
                acc[i][2] = fmaf(a[i].x, b[0].z, acc[i][2]);
                acc[i][3] = fmaf(a[i].x, b[0].w, acc[i][3]);
                acc[i][0] = fmaf(a[i].y, b[1].x, acc[i][0]);
                acc[i][1] = fmaf(a[i].y, b[1].y, acc[i][1]);
                acc[i][2] = fmaf(a[i].y, b[1].z, acc[i][2]);
                acc[i][3] = fmaf(a[i].y, b[1].w, acc[i][3]);
                acc[i][0] = fmaf(a[i].z, b[2].x, acc[i][0]);
                acc[i][1] = fmaf(a[i].z, b[2].y, acc[i][1]);
                acc[i][2] = fmaf(a[i].z, b[2].z, acc[i][2]);
                acc[i][3] = fmaf(a[i].z, b[2].w, acc[i][3]);
                acc[i][0] = fmaf(a[i].w, b[3].x, acc[i][0]);
                acc[i][1] = fmaf(a[i].w, b[3].y, acc[i][1]);
                acc[i][2] = fmaf(a[i].w, b[3].z, acc[i][2]);
                acc[i][3] = fmaf(a[i].w, b[3].w, acc[i][3]);
            }
        }
    }

#pragma unroll
    for (int i = 0; i < 4; i++) {
        int gr = row0 + ty * 4 + i;
        if (gr < n) {
            float sc = dinv[gr];
            *(float4*)(out + (size_t)gr * HID + tx * 4) =
                make_float4(acc[i][0] * sc, acc[i][1] * sc, acc[i][2] * sc, acc[i][3] * sc);
        }
    }
}

// ---------------- CSR gather aggregation (fused selfloop + bias + relu [+ logits]) ----

template<bool LOGITS>
__global__ void gather_k(const float* __restrict__ tS, const int* __restrict__ rowptr,
                         const int* __restrict__ col, const float* __restrict__ dinv,
                         const float* __restrict__ b, float* __restrict__ out,
                         const float* __restrict__ Wa, const float* __restrict__ ba,
                         float* __restrict__ logits, int n) {
    int node = (int)((blockIdx.x * (size_t)blockDim.x + threadIdx.x) >> 6);
    int lane = threadIdx.x & 63;
    if (node >= n) return;
    int beg = rowptr[node], end = rowptr[node + 1];
    const float* tl = tS + lane;
    float acc = tl[(size_t)node * HID];   // self-loop term
    int e = beg;
    for (; e + 16 <= end; e += 16) {
        int s[16];
        float v[16];
#pragma unroll
        for (int j = 0; j < 16; j++) s[j] = col[e + j];
#pragma unroll
        for (int j = 0; j < 16; j++) v[j] = tl[(size_t)s[j] * HID];
        float t0 = ((v[0] + v[1]) + (v[2] + v[3])) + ((v[4] + v[5]) + (v[6] + v[7]));
        float t1 = ((v[8] + v[9]) + (v[10] + v[11])) + ((v[12] + v[13]) + (v[14] + v[15]));
        acc += t0 + t1;
    }
    for (; e + 4 <= end; e += 4) {
        int s0 = col[e], s1 = col[e + 1], s2 = col[e + 2], s3 = col[e + 3];
        float v0 = tl[(size_t)s0 * HID];
        float v1 = tl[(size_t)s1 * HID];
        float v2 = tl[(size_t)s2 * HID];
        float v3 = tl[(size_t)s3 * HID];
        acc += (v0 + v1) + (v2 + v3);
    }
    for (; e < end; ++e) acc += tl[(size_t)col[e] * HID];
    float h = fmaxf(fmaf(dinv[node], acc, b[lane]), 0.0f);
    out[(size_t)node * HID + lane] = h;
    if (LOGITS) {
        float p = h * Wa[lane];
#pragma unroll
        for (int off = 32; off > 0; off >>= 1) p += __shfl_down(p, off);
        if (lane == 0) logits[node] = p + ba[0];
    }
}

// ---------------- heads ----------------

__global__ void pool_k(const float* __restrict__ h, const int* __restrict__ batch,
                       float* __restrict__ pooled, float* __restrict__ counts, int n) {
    int lane = threadIdx.x & 63;
    int wave = threadIdx.x >> 6;
    int start = blockIdx.x * 256 + wave * 64;
    int end   = min(start + 64, n);
    if (start >= end) return;
    float acc = 0.0f;
    int curg = -1, cnt = 0;
    for (int i = start; i < end; i++) {
        int g = batch[i];
        if (g != curg) {
            if (curg >= 0) {
                atomicAdd(&pooled[curg * HID + lane], acc);
                if (lane == 0) atomicAdd(&counts[curg], (float)cnt);
            }
            curg = g; acc = 0.0f; cnt = 0;
        }
        acc += h[(size_t)i * HID + lane];
        cnt++;
    }
    atomicAdd(&pooled[curg * HID + lane], acc);
    if (lane == 0) atomicAdd(&counts[curg], (float)cnt);
}

__global__ void value_k(const float* __restrict__ pooled, const float* __restrict__ counts,
                        const float* __restrict__ Wc, const float* __restrict__ bc,
                        float* __restrict__ val, int g) {
    int gw   = (int)((blockIdx.x * (size_t)blockDim.x + threadIdx.x) >> 6);
    int lane = threadIdx.x & 63;
    if (gw >= g) return;
    float cnt = fmaxf(counts[gw], 1.0f);
    float p = (pooled[gw * HID + lane] / cnt) * Wc[lane];
#pragma unroll
    for (int off = 32; off > 0; off >>= 1) p += __shfl_down(p, off);
    if (lane == 0) val[gw] = p + bc[0];
}

extern "C" void kernel_launch(void* const* d_in, const int* in_sizes, int n_in,
                              void* d_out, int out_size, void* d_ws, size_t ws_size,
                              hipStream_t stream) {
    const float* x     = (const float*)d_in[0];
    const int*   ei    = (const int*)d_in[1];
    const int*   batch = (const int*)d_in[2];
    const float* W1    = (const float*)d_in[3];
    const float* b1    = (const float*)d_in[4];
    const float* W2    = (const float*)d_in[5];
    const float* b2    = (const float*)d_in[6];
    const float* Wa    = (const float*)d_in[7];
    const float* ba    = (const float*)d_in[8];
    const float* Wc    = (const float*)d_in[9];
    const float* bc    = (const float*)d_in[10];

    const int n = in_sizes[0] / FEAT;   // 100000
    const int e = in_sizes[1] / 2;      // 1600000
    const int g = out_size - n;         // 64
    const int* src = ei;
    const int* dst = ei + e;

    const int nb = (n + BNODES - 1) >> BSH;   // buckets (782)
    const int L  = nb * PB;                    // offset table length

    // workspace layout (packed aliases bufA: dead before first gemm)
    float*    ws     = (float*)d_ws;
    float*    dinv   = ws;                               // n
    float*    bufA   = dinv + n;                         // n*HID  (tS)
    float*    bufB   = bufA + (size_t)n * HID;           // n*HID  (h)
    float*    pooled = bufB + (size_t)n * HID;           // g*HID
    float*    counts = pooled + (size_t)g * HID;         // g
    int*      table  = (int*)(counts + g);               // L
    int*      aux    = table + L;                        // 1024
    int*      rowptr = aux + 1024;                       // n+1
    int*      col    = rowptr + n + 1;                   // e
    unsigned* packed = (unsigned*)bufA;                  // e (aliased, transient)

    const int B = 256;
    const int gridT = (n + 63) / 64;
    const int gridG = (int)(((size_t)n * 64 + B - 1) / B);   // wave per node
    const int nb1   = (L + 1023) / 1024;

    hipMemsetAsync(pooled, 0, (size_t)(g * HID + g) * sizeof(float), stream);

    // two-level CSR build: bucket partition -> in-bucket counting sort
    part_hist_k<<<PB, B, 0, stream>>>(dst, table, e, nb);
    scan1_k<<<nb1, 1024, 0, stream>>>(table, aux, L);
    scan2_k<<<1, 1024, 0, stream>>>(aux, nb1);
    part_scatter_k<<<PB, B, 0, stream>>>(src, dst, table, aux, packed, e, nb);
    bucket_sort_k<<<nb, B, 0, stream>>>(packed, table, aux, col, rowptr, dinv, n, e, nb);

    // layer 1
    gemm_tile_k<FEAT><<<gridT, B, 0, stream>>>(x, W1, dinv, bufA, n);
    gather_k<false><<<gridG, B, 0, stream>>>(bufA, rowptr, col, dinv, b1, bufB,
                                             nullptr, nullptr, nullptr, n);

    // layer 2 (logits fused into gather epilogue)
    gemm_tile_k<HID><<<gridT, B, 0, stream>>>(bufB, W2, dinv, bufA, n);
    gather_k<true><<<gridG, B, 0, stream>>>(bufA, rowptr, col, dinv, b2, bufB,
                                            Wa, ba, (float*)d_out, n);

    // heads
    pool_k<<<(n + 255) / 256, B, 0, stream>>>(bufB, batch, pooled, counts, n);
    value_k<<<(g * 64 + B - 1) / B, B, 0, stream>>>(pooled, counts, Wc, bc, (float*)d_out + n, g);
}